// Round 3
// baseline (182.816 us; speedup 1.0000x reference)
//
#include <hip/hip_runtime.h>
#include <stdint.h>

typedef __attribute__((ext_vector_type(8))) short bh8;    // 8 bf16 = 4 VGPR (MFMA A/B frag)
typedef __attribute__((ext_vector_type(4))) float f32x4;  // MFMA C/D frag
typedef unsigned int uint32;

__device__ __forceinline__ unsigned short f2bf(float f) {
  uint32 u = __builtin_bit_cast(uint32, f);
  u += 0x7fffu + ((u >> 16) & 1u);   // RNE
  return (unsigned short)(u >> 16);
}

// global -> LDS direct (16B/lane). LDS dest must be uniform-base + lane*16 (linear);
// swizzling is done on the GLOBAL source address (guide §5 / rule 21).
__device__ __forceinline__ void lds_load16(const void* g, void* l) {
  auto gp = (const __attribute__((address_space(1))) uint32*)(uintptr_t)(g);
  auto lp = (__attribute__((address_space(3))) uint32*)(uintptr_t)(l);
  __builtin_amdgcn_global_load_lds(gp, lp, 16, 0, 0);
}

// ---------------------------------------------------------------------------
// Transpose hidden (t,c,p) -> x_bf16[n=t*256+p][c], and W (c,d) -> Wt_bf16[d][c].
// blockIdx.x < 32: t-slab of hidden. 32..34: Wq/Wk/Wv (scale 1/16 folded into Wq).
// Per block: 256 p/d rows x 16 c columns. LDS 9KB.
__global__ __launch_bounds__(256) void k_transpose(
    const float* __restrict__ hidden, const float* __restrict__ Wq,
    const float* __restrict__ Wk, const float* __restrict__ Wv,
    unsigned short* __restrict__ xb, unsigned short* __restrict__ wt) {
  int bid = blockIdx.x, c0 = blockIdx.y * 16, tid = threadIdx.x;
  const float* in; unsigned short* out; float scale = 1.0f;
  if (bid < 32) { in = hidden + (size_t)bid * 65536; out = xb + (size_t)bid * 65536; }
  else {
    int j = bid - 32;
    in = (j == 0) ? Wq : (j == 1 ? Wk : Wv);
    out = wt + (size_t)j * 65536;
    if (j == 0) scale = 0.0625f;   // 1/sqrt(256)
  }
  __shared__ uint32 lt[256 * 9];
  uint32 pk[8];
#pragma unroll
  for (int i = 0; i < 8; ++i) {
    float a = in[(size_t)(c0 + 2 * i) * 256 + tid] * scale;      // coalesced along p
    float b = in[(size_t)(c0 + 2 * i + 1) * 256 + tid] * scale;
    pk[i] = (uint32)f2bf(a) | ((uint32)f2bf(b) << 16);
  }
#pragma unroll
  for (int i = 0; i < 8; ++i) lt[tid * 9 + i] = pk[i];
  __syncthreads();
  int q2 = tid & 1;
#pragma unroll
  for (int rr = 0; rr < 2; ++rr) {
    int r = rr * 128 + (tid >> 1);
    uint4 v;
    v.x = lt[r * 9 + q2 * 4 + 0]; v.y = lt[r * 9 + q2 * 4 + 1];
    v.z = lt[r * 9 + q2 * 4 + 2]; v.w = lt[r * 9 + q2 * 4 + 3];
    *(uint4*)(out + (size_t)r * 256 + c0 + q2 * 8) = v;          // 16B coalesced
  }
}

// ---------------------------------------------------------------------------
// GEMM: z=0: q = x*WqT_t, z=1: k = x*WkT_t (row-major [n][d]),
//       z=2: vT[d][n] = (WvT * xT)  (operand-swapped so output is d-major).
// 128x128 tile, BK=64, 4 waves (2x2), 16x16x32 bf16 MFMA.
__global__ __launch_bounds__(256, 2) void k_gemm(
    const unsigned short* __restrict__ xb, const unsigned short* __restrict__ wt,
    unsigned short* __restrict__ qb, unsigned short* __restrict__ kb,
    unsigned short* __restrict__ vtb) {
  __shared__ char lds[32768];
  char* ldsA = lds; char* ldsB = lds + 16384;
  int tid = threadIdx.x, z = blockIdx.z;
  int l = tid & 63, w = tid >> 6, g = l >> 4, r15 = l & 15;
  int wr = w >> 1, wc = w & 1;
  const unsigned short *Ag, *Bg; unsigned short* out;
  int arow0, brow0; size_t ostride;
  if (z < 2) {
    Ag = xb; arow0 = blockIdx.x * 128;
    Bg = wt + (size_t)z * 65536; brow0 = blockIdx.y * 128;
    out = z ? kb : qb; ostride = 256;
  } else {
    Ag = wt + 2 * 65536; arow0 = blockIdx.y * 128;
    Bg = xb; brow0 = blockIdx.x * 128;
    out = vtb; ostride = 8192;
  }
  f32x4 acc[4][4];
#pragma unroll
  for (int i = 0; i < 4; ++i)
#pragma unroll
    for (int j = 0; j < 4; ++j) acc[i][j] = (f32x4){0.f, 0.f, 0.f, 0.f};

  for (int kk = 0; kk < 4; ++kk) {
    int c0 = kk * 64;
    __syncthreads();
#pragma unroll
    for (int p = 0; p < 4; ++p) {     // A tile [128][64] bf16, swizzled chunks
      int off = p * 4096 + tid * 16;
      int row = off >> 7, ch = (off >> 4) & 7, sc = ch ^ (row & 7);
      lds_load16((const char*)Ag + ((size_t)(arow0 + row) * 256 + c0) * 2 + sc * 16, ldsA + off);
    }
#pragma unroll
    for (int p = 0; p < 4; ++p) {     // B tile [128][64] bf16 (col-major tile), swizzled
      int off = p * 4096 + tid * 16;
      int row = off >> 7, ch = (off >> 4) & 7, sc = ch ^ (row & 7);
      lds_load16((const char*)Bg + ((size_t)(brow0 + row) * 256 + c0) * 2 + sc * 16, ldsB + off);
    }
    __syncthreads();
#pragma unroll
    for (int ks = 0; ks < 2; ++ks) {
      bh8 af[4], bfr[4];
#pragma unroll
      for (int i = 0; i < 4; ++i) {
        int rowa = wr * 64 + i * 16 + r15;
        af[i] = *(const bh8*)(ldsA + rowa * 128 + (((ks * 4 + g) ^ (rowa & 7)) * 16));
        int rowb = wc * 64 + i * 16 + r15;
        bfr[i] = *(const bh8*)(ldsB + rowb * 128 + (((ks * 4 + g) ^ (rowb & 7)) * 16));
      }
#pragma unroll
      for (int i = 0; i < 4; ++i)
#pragma unroll
        for (int j = 0; j < 4; ++j)
          acc[i][j] = __builtin_amdgcn_mfma_f32_16x16x32_bf16(af[i], bfr[j], acc[i][j], 0, 0, 0);
    }
  }
  __syncthreads();
  // bounce C (bf16) through LDS for coalesced stores
#pragma unroll
  for (int i = 0; i < 4; ++i)
#pragma unroll
    for (int j = 0; j < 4; ++j)
#pragma unroll
      for (int r = 0; r < 4; ++r) {
        int rowl = wr * 64 + i * 16 + g * 4 + r;   // C/D: row=(l>>4)*4+reg
        int coll = wc * 64 + j * 16 + r15;         //      col=l&15
        *(unsigned short*)(lds + rowl * 256 + coll * 2) = f2bf(acc[i][j][r]);
      }
  __syncthreads();
#pragma unroll
  for (int p = 0; p < 8; ++p) {
    int off = p * 4096 + tid * 16;
    int row = off >> 8, colb = off & 255;
    *(uint4*)((char*)out + ((size_t)(arow0 + row) * ostride + (size_t)brow0) * 2 + colb) =
        *(const uint4*)(lds + off);
  }
}

// ---------------------------------------------------------------------------
// Flash attention. QBLK=128 (8 waves x 16 rows), KVBLK=64, KV split S-ways.
// 64KB static LDS: K tile [64][256] bf16 (32KB) + VT tile [256][64] bf16 (32KB),
// both 16B-chunk XOR-swizzled. Per-wave P bounce buffers OVERLAY the K region
// (K is dead after QK^T); a barrier separates the last K-read from the P-write.
__global__ __launch_bounds__(512, 2) void k_attn(
    const unsigned short* __restrict__ qg, const unsigned short* __restrict__ kg,
    const unsigned short* __restrict__ vtg, float* __restrict__ Op,
    float* __restrict__ mp, float* __restrict__ lp, int S, int shift, int KS) {
  __shared__ char smem[65536];
  char* Kl = smem;             // 32KB
  char* Vl = smem + 32768;     // 32KB
  int tid = threadIdx.x;
  int w = tid >> 6, l = tid & 63, g = l >> 4, r15 = l & 15;
  char* Pl = smem + w * 2048;  // per-wave 16x64 bf16, OVERLAYS K tile (barrier-guarded)
  int bid = blockIdx.x;
  int s = (bid >> 1) & (S - 1);                      // KV-slice; pairs of XCDs share a slice
  int qb = ((bid >> (1 + shift)) << 1) | (bid & 1);
  int qrow0 = qb * 128 + w * 16;

  bh8 qf[8];                                          // Q hoisted: 16 rows x 256 d
  const char* qrow = (const char*)qg + (size_t)(qrow0 + r15) * 512;
#pragma unroll
  for (int ds = 0; ds < 8; ++ds) qf[ds] = *(const bh8*)(qrow + ds * 64 + g * 16);

  f32x4 o[16];
#pragma unroll
  for (int dt = 0; dt < 16; ++dt) o[dt] = (f32x4){0.f, 0.f, 0.f, 0.f};
  float m[4], ls[4];
#pragma unroll
  for (int r = 0; r < 4; ++r) { m[r] = -INFINITY; ls[r] = 0.f; }

  int nt = KS >> 6, kb0 = s * KS;
  for (int kt = 0; kt < nt; ++kt) {
    int kvb = kb0 + kt * 64;
    __syncthreads();                 // prev iter's P/V reads drained; safe to overwrite
#pragma unroll
    for (int p = 0; p < 4; ++p) {   // K tile: rows 512B = 32 chunks, swizzle ^ (row&7)
      int off = p * 8192 + tid * 16;
      int row = off >> 9, ch = (off >> 4) & 31;
      lds_load16((const char*)kg + (size_t)(kvb + row) * 512 + ((ch ^ (row & 7)) * 16), Kl + off);
    }
#pragma unroll
    for (int p = 0; p < 4; ++p) {   // VT tile: 256 rows x 128B = 8 chunks
      int off = p * 8192 + tid * 16;
      int row = off >> 7, ch = (off >> 4) & 7;
      lds_load16((const char*)vtg + (size_t)row * 16384 + (size_t)kvb * 2 + ((ch ^ (row & 7)) * 16),
                 Vl + off);
    }
    __syncthreads();

    // S = Q*K^T (scale pre-folded into Wq)
    f32x4 s4[4];
#pragma unroll
    for (int it = 0; it < 4; ++it) s4[it] = (f32x4){0.f, 0.f, 0.f, 0.f};
#pragma unroll
    for (int ds = 0; ds < 8; ++ds)
#pragma unroll
      for (int it = 0; it < 4; ++it) {
        int krow = it * 16 + r15;
        bh8 kf = *(const bh8*)(Kl + krow * 512 + (((ds * 4 + g) ^ (krow & 7)) * 16));
        s4[it] = __builtin_amdgcn_mfma_f32_16x16x32_bf16(qf[ds], kf, s4[it], 0, 0, 0);
      }

    // online softmax over 64 keys (rows live in 16-lane groups)
    float rmax[4];
#pragma unroll
    for (int r = 0; r < 4; ++r)
      rmax[r] = fmaxf(fmaxf(s4[0][r], s4[1][r]), fmaxf(s4[2][r], s4[3][r]));
#pragma unroll
    for (int d = 1; d < 16; d <<= 1)
#pragma unroll
      for (int r = 0; r < 4; ++r) rmax[r] = fmaxf(rmax[r], __shfl_xor(rmax[r], d));
    float scl[4];
#pragma unroll
    for (int r = 0; r < 4; ++r) {
      float mn = fmaxf(m[r], rmax[r]);
      scl[r] = __expf(m[r] - mn);
      m[r] = mn;
    }
    float rsum[4] = {0.f, 0.f, 0.f, 0.f};
#pragma unroll
    for (int it = 0; it < 4; ++it)
#pragma unroll
      for (int r = 0; r < 4; ++r) {
        float pv = __expf(s4[it][r] - m[r]);
        s4[it][r] = pv;
        rsum[r] += pv;
      }
#pragma unroll
    for (int d = 1; d < 16; d <<= 1)
#pragma unroll
      for (int r = 0; r < 4; ++r) rsum[r] += __shfl_xor(rsum[r], d);
    f32x4 sv = {scl[0], scl[1], scl[2], scl[3]};
#pragma unroll
    for (int r = 0; r < 4; ++r) ls[r] = ls[r] * scl[r] + rsum[r];
#pragma unroll
    for (int dt = 0; dt < 16; ++dt) o[dt] *= sv;

    __syncthreads();   // ALL waves done reading K tile -> safe to overlay P into it

    // P -> per-wave LDS (bf16, swizzled), then read back as PV A-fragments
#pragma unroll
    for (int it = 0; it < 4; ++it)
#pragma unroll
      for (int r = 0; r < 4; ++r) {
        int prow = g * 4 + r;
        int ch = (it * 2 + (r15 >> 3)) ^ (prow & 7);
        *(unsigned short*)(Pl + prow * 128 + ch * 16 + (r15 & 7) * 2) = f2bf(s4[it][r]);
      }
    asm volatile("s_waitcnt lgkmcnt(0)" ::: "memory");
    bh8 pa[2];
#pragma unroll
    for (int ks = 0; ks < 2; ++ks)
      pa[ks] = *(const bh8*)(Pl + r15 * 128 + (((ks * 4 + g) ^ (r15 & 7)) * 16));
#pragma unroll
    for (int ks = 0; ks < 2; ++ks)
#pragma unroll
      for (int dt = 0; dt < 16; ++dt) {
        int vrow = dt * 16 + r15;
        bh8 vf = *(const bh8*)(Vl + vrow * 128 + (((ks * 4 + g) ^ (vrow & 7)) * 16));
        o[dt] = __builtin_amdgcn_mfma_f32_16x16x32_bf16(pa[ks], vf, o[dt], 0, 0, 0);
      }
  }

  // partials
  int nrow = qrow0 + g * 4;
  float* ob = Op + ((size_t)s * 8192 + nrow) * 256 + r15;
#pragma unroll
  for (int r = 0; r < 4; ++r)
#pragma unroll
    for (int dt = 0; dt < 16; ++dt) ob[(size_t)r * 256 + dt * 16] = o[dt][r];
  if (r15 == 0) {
#pragma unroll
    for (int r = 0; r < 4; ++r) {
      mp[(size_t)s * 8192 + nrow + r] = m[r];
      lp[(size_t)s * 8192 + nrow + r] = ls[r];
    }
  }
}

// ---------------------------------------------------------------------------
// Split-K combine + normalize + output transpose to (t, d, p).
// Block = (t, 32-wide d-chunk). Phase A: per-row merge weights (one thread per p).
// Phase B: accumulate all 256 p x 32 d; transpose via LDS; coalesced stores.
__global__ __launch_bounds__(256) void k_combine(
    const float* __restrict__ Op, const float* __restrict__ mp,
    const float* __restrict__ lp, float* __restrict__ out, int S) {
  __shared__ float wsc[4 * 256];
  __shared__ float lt[32 * 257];
  int t = blockIdx.x, dc = blockIdx.y, tid = threadIdx.x;
  {
    int n = t * 256 + tid;
    float mt = -INFINITY;
#pragma unroll 4
    for (int s = 0; s < 4; ++s)
      if (s < S) mt = fmaxf(mt, mp[(size_t)s * 8192 + n]);
    float den = 0.f;
#pragma unroll 4
    for (int s = 0; s < 4; ++s)
      if (s < S) den += __expf(mp[(size_t)s * 8192 + n] - mt) * lp[(size_t)s * 8192 + n];
    float inv = 1.0f / den;
#pragma unroll 4
    for (int s = 0; s < 4; ++s)
      if (s < S) wsc[s * 256 + tid] = __expf(mp[(size_t)s * 8192 + n] - mt) * inv;
  }
  __syncthreads();
  int dl = tid & 31, pg8 = tid >> 5;   // 32 d-lanes x 8 p-rows per pass
  for (int pg = 0; pg < 32; ++pg) {
    int p = pg * 8 + pg8;
    int n = t * 256 + p;
    float a = 0.f;
#pragma unroll 4
    for (int s = 0; s < 4; ++s)
      if (s < S) a += wsc[s * 256 + p] * Op[((size_t)s * 8192 + n) * 256 + dc * 32 + dl];
    lt[dl * 257 + p] = a;
  }
  __syncthreads();
  int d8 = tid >> 5, p0 = (tid & 31) * 8;
#pragma unroll
  for (int jj = 0; jj < 4; ++jj) {
    int dd = jj * 8 + d8;
    float4 v0, v1;
    v0.x = lt[dd * 257 + p0 + 0]; v0.y = lt[dd * 257 + p0 + 1];
    v0.z = lt[dd * 257 + p0 + 2]; v0.w = lt[dd * 257 + p0 + 3];
    v1.x = lt[dd * 257 + p0 + 4]; v1.y = lt[dd * 257 + p0 + 5];
    v1.z = lt[dd * 257 + p0 + 6]; v1.w = lt[dd * 257 + p0 + 7];
    float* ob = out + (size_t)t * 65536 + (size_t)(dc * 32 + dd) * 256 + p0;
    *(float4*)ob = v0;
    *(float4*)(ob + 4) = v1;
  }
}

// ---------------------------------------------------------------------------
extern "C" void kernel_launch(void* const* d_in, const int* in_sizes, int n_in,
                              void* d_out, int out_size, void* d_ws, size_t ws_size,
                              hipStream_t stream) {
  const float* hidden = (const float*)d_in[0];
  const float* Wq = (const float*)d_in[1];
  const float* Wk = (const float*)d_in[2];
  const float* Wv = (const float*)d_in[3];
  float* out = (float*)d_out;
  char* ws = (char*)d_ws;

  const size_t off_x  = 0;                               // x_bf16: 4MB
  const size_t off_wt = 4ull << 20;                      // 3 x 128KB
  const size_t off_q  = off_wt + 3ull * 131072;
  const size_t off_k  = off_q + 8192ull * 256 * 2;
  const size_t off_vt = off_k + 8192ull * 256 * 2;
  const size_t off_O  = off_vt + 8192ull * 256 * 2;

  int S = 4;
  {
    auto need = [&](int s) {
      return off_O + (size_t)s * 8192 * 256 * 4 + (size_t)s * 8192 * 4 * 2;
    };
    if (ws_size < need(4)) S = 2;
    if (ws_size < need(2)) S = 1;
  }
  size_t off_m = off_O + (size_t)S * 8192 * 256 * 4;
  size_t off_l = off_m + (size_t)S * 8192 * 4;

  unsigned short* xb  = (unsigned short*)(ws + off_x);
  unsigned short* wt  = (unsigned short*)(ws + off_wt);
  unsigned short* qb  = (unsigned short*)(ws + off_q);
  unsigned short* kb  = (unsigned short*)(ws + off_k);
  unsigned short* vtb = (unsigned short*)(ws + off_vt);
  float* Op = (float*)(ws + off_O);
  float* mp = (float*)(ws + off_m);
  float* lp = (float*)(ws + off_l);
  int shift = (S == 4) ? 2 : (S == 2 ? 1 : 0);
  int KS = 8192 / S;

  k_transpose<<<dim3(35, 16), dim3(256), 0, stream>>>(hidden, Wq, Wk, Wv, xb, wt);
  k_gemm<<<dim3(64, 2, 3), dim3(256), 0, stream>>>(xb, wt, qb, kb, vtb);
  k_attn<<<dim3(64 * S), dim3(512), 0, stream>>>(qb, kb, vtb, Op, mp, lp, S, shift, KS);
  k_combine<<<dim3(32, 8), dim3(256), 0, stream>>>(Op, mp, lp, out, S);
}

// Round 4
// 173.534 us; speedup vs baseline: 1.0535x; 1.0535x over previous
//
#include <hip/hip_runtime.h>
#include <stdint.h>

typedef __attribute__((ext_vector_type(8))) short bh8;    // 8 bf16 = 4 VGPR (MFMA A/B frag)
typedef __attribute__((ext_vector_type(4))) short bh4;    // 4 bf16 = 2 VGPR
typedef __attribute__((ext_vector_type(4))) float f32x4;  // MFMA C/D frag
typedef unsigned int uint32;

__device__ __forceinline__ unsigned short f2bf(float f) {
  uint32 u = __builtin_bit_cast(uint32, f);
  u += 0x7fffu + ((u >> 16) & 1u);   // RNE
  return (unsigned short)(u >> 16);
}

// global -> LDS direct (16B/lane). LDS dest must be uniform-base + lane*16 (linear);
// swizzling is done on the GLOBAL source address (guide §5 / rule 21).
__device__ __forceinline__ void lds_load16(const void* g, void* l) {
  auto gp = (const __attribute__((address_space(1))) uint32*)(uintptr_t)(g);
  auto lp = (__attribute__((address_space(3))) uint32*)(uintptr_t)(l);
  __builtin_amdgcn_global_load_lds(gp, lp, 16, 0, 0);
}

// ---------------------------------------------------------------------------
// Transpose hidden (t,c,p) -> x_bf16[n=t*256+p][c], and W (c,d) -> Wt_bf16[d][c].
__global__ __launch_bounds__(256) void k_transpose(
    const float* __restrict__ hidden, const float* __restrict__ Wq,
    const float* __restrict__ Wk, const float* __restrict__ Wv,
    unsigned short* __restrict__ xb, unsigned short* __restrict__ wt) {
  int bid = blockIdx.x, c0 = blockIdx.y * 16, tid = threadIdx.x;
  const float* in; unsigned short* out; float scale = 1.0f;
  if (bid < 32) { in = hidden + (size_t)bid * 65536; out = xb + (size_t)bid * 65536; }
  else {
    int j = bid - 32;
    in = (j == 0) ? Wq : (j == 1 ? Wk : Wv);
    out = wt + (size_t)j * 65536;
    if (j == 0) scale = 0.0625f;   // 1/sqrt(256)
  }
  __shared__ uint32 lt[256 * 9];
  uint32 pk[8];
#pragma unroll
  for (int i = 0; i < 8; ++i) {
    float a = in[(size_t)(c0 + 2 * i) * 256 + tid] * scale;      // coalesced along p
    float b = in[(size_t)(c0 + 2 * i + 1) * 256 + tid] * scale;
    pk[i] = (uint32)f2bf(a) | ((uint32)f2bf(b) << 16);
  }
#pragma unroll
  for (int i = 0; i < 8; ++i) lt[tid * 9 + i] = pk[i];
  __syncthreads();
  int q2 = tid & 1;
#pragma unroll
  for (int rr = 0; rr < 2; ++rr) {
    int r = rr * 128 + (tid >> 1);
    uint4 v;
    v.x = lt[r * 9 + q2 * 4 + 0]; v.y = lt[r * 9 + q2 * 4 + 1];
    v.z = lt[r * 9 + q2 * 4 + 2]; v.w = lt[r * 9 + q2 * 4 + 3];
    *(uint4*)(out + (size_t)r * 256 + c0 + q2 * 8) = v;          // 16B coalesced
  }
}

// ---------------------------------------------------------------------------
// GEMM: z=0: q = x*WqT_t, z=1: k = x*WkT_t (row-major [n][d]),
//       z=2: vT[d][n] = (WvT * xT)  (operand-swapped so output is d-major).
__global__ __launch_bounds__(256, 2) void k_gemm(
    const unsigned short* __restrict__ xb, const unsigned short* __restrict__ wt,
    unsigned short* __restrict__ qb, unsigned short* __restrict__ kb,
    unsigned short* __restrict__ vtb) {
  __shared__ char lds[32768];
  char* ldsA = lds; char* ldsB = lds + 16384;
  int tid = threadIdx.x, z = blockIdx.z;
  int l = tid & 63, w = tid >> 6, g = l >> 4, r15 = l & 15;
  int wr = w >> 1, wc = w & 1;
  const unsigned short *Ag, *Bg; unsigned short* out;
  int arow0, brow0; size_t ostride;
  if (z < 2) {
    Ag = xb; arow0 = blockIdx.x * 128;
    Bg = wt + (size_t)z * 65536; brow0 = blockIdx.y * 128;
    out = z ? kb : qb; ostride = 256;
  } else {
    Ag = wt + 2 * 65536; arow0 = blockIdx.y * 128;
    Bg = xb; brow0 = blockIdx.x * 128;
    out = vtb; ostride = 8192;
  }
  f32x4 acc[4][4];
#pragma unroll
  for (int i = 0; i < 4; ++i)
#pragma unroll
    for (int j = 0; j < 4; ++j) acc[i][j] = (f32x4){0.f, 0.f, 0.f, 0.f};

  for (int kk = 0; kk < 4; ++kk) {
    int c0 = kk * 64;
    __syncthreads();
#pragma unroll
    for (int p = 0; p < 4; ++p) {     // A tile [128][64] bf16, swizzled chunks
      int off = p * 4096 + tid * 16;
      int row = off >> 7, ch = (off >> 4) & 7, sc = ch ^ (row & 7);
      lds_load16((const char*)Ag + ((size_t)(arow0 + row) * 256 + c0) * 2 + sc * 16, ldsA + off);
    }
#pragma unroll
    for (int p = 0; p < 4; ++p) {     // B tile [128][64] bf16 (col-major tile), swizzled
      int off = p * 4096 + tid * 16;
      int row = off >> 7, ch = (off >> 4) & 7, sc = ch ^ (row & 7);
      lds_load16((const char*)Bg + ((size_t)(brow0 + row) * 256 + c0) * 2 + sc * 16, ldsB + off);
    }
    __syncthreads();
#pragma unroll
    for (int ks = 0; ks < 2; ++ks) {
      bh8 af[4], bfr[4];
#pragma unroll
      for (int i = 0; i < 4; ++i) {
        int rowa = wr * 64 + i * 16 + r15;
        af[i] = *(const bh8*)(ldsA + rowa * 128 + (((ks * 4 + g) ^ (rowa & 7)) * 16));
        int rowb = wc * 64 + i * 16 + r15;
        bfr[i] = *(const bh8*)(ldsB + rowb * 128 + (((ks * 4 + g) ^ (rowb & 7)) * 16));
      }
#pragma unroll
      for (int i = 0; i < 4; ++i)
#pragma unroll
        for (int j = 0; j < 4; ++j)
          acc[i][j] = __builtin_amdgcn_mfma_f32_16x16x32_bf16(af[i], bfr[j], acc[i][j], 0, 0, 0);
    }
  }
  __syncthreads();
  // bounce C (bf16) through LDS for coalesced stores
#pragma unroll
  for (int i = 0; i < 4; ++i)
#pragma unroll
    for (int j = 0; j < 4; ++j)
#pragma unroll
      for (int r = 0; r < 4; ++r) {
        int rowl = wr * 64 + i * 16 + g * 4 + r;   // C/D: row=(l>>4)*4+reg
        int coll = wc * 64 + j * 16 + r15;         //      col=l&15
        *(unsigned short*)(lds + rowl * 256 + coll * 2) = f2bf(acc[i][j][r]);
      }
  __syncthreads();
#pragma unroll
  for (int p = 0; p < 8; ++p) {
    int off = p * 4096 + tid * 16;
    int row = off >> 8, colb = off & 255;
    *(uint4*)((char*)out + ((size_t)(arow0 + row) * ostride + (size_t)brow0) * 2 + colb) =
        *(const uint4*)(lds + off);
  }
}

// ---------------------------------------------------------------------------
// Flash attention. QBLK=128 (8 waves x 16 rows), KVBLK=64, KV split S-ways.
// Double-buffered K/V in dynamic LDS (145KB): K0,V0,K1,V1 @32KB each + per-wave
// P (16x[136B] rows). Schedule per iter (T3/T4 minimum recipe):
//   stage(buf^1) ; s_waitcnt vmcnt(8) ; s_barrier ; compute(buf cur) ;
//   s_waitcnt lgkmcnt(0) ; s_barrier
// vmcnt(8) waits only on the PREVIOUS iteration's 8 loads (long done) ->
// staging latency fully hidden under compute; no vmcnt(0) drain in the loop.
__global__ __launch_bounds__(512, 2) void k_attn(
    const unsigned short* __restrict__ qg, const unsigned short* __restrict__ kg,
    const unsigned short* __restrict__ vtg, float* __restrict__ Op,
    float* __restrict__ mp, float* __restrict__ lp, int S, int shift, int KS) {
  extern __shared__ char smem[];
  int tid = threadIdx.x;
  int w = tid >> 6, l = tid & 63, g = l >> 4, r15 = l & 15;
  char* Pl = smem + 131072 + w * 2176;   // per-wave 16 rows x 136B
  int bid = blockIdx.x;
  int s = (bid >> 1) & (S - 1);                      // KV-slice; pairs of XCDs share a slice
  int qb = ((bid >> (1 + shift)) << 1) | (bid & 1);
  int qrow0 = qb * 128 + w * 16;

  bh8 qf[8];                                          // Q hoisted: 16 rows x 256 d
  const char* qrow = (const char*)qg + (size_t)(qrow0 + r15) * 512;
#pragma unroll
  for (int ds = 0; ds < 8; ++ds) qf[ds] = *(const bh8*)(qrow + ds * 64 + g * 16);
  asm volatile("s_waitcnt vmcnt(0)" ::: "memory");    // exact vmcnt bookkeeping below

  f32x4 o[16];
#pragma unroll
  for (int dt = 0; dt < 16; ++dt) o[dt] = (f32x4){0.f, 0.f, 0.f, 0.f};
  float m[4], ls[4];
#pragma unroll
  for (int r = 0; r < 4; ++r) { m[r] = -INFINITY; ls[r] = 0.f; }

  int nt = KS >> 6, kb0 = s * KS;

  // stage one KV tile (8 global_load_lds per wave = 64KB per block)
  auto stage = [&](int buf, int kvb) {
    char* Kd = smem + buf * 65536;
    char* Vd = Kd + 32768;
#pragma unroll
    for (int p = 0; p < 4; ++p) {   // K tile [64][256]: rows 512B = 32 chunks, swz ^ (row&7)
      int off = p * 8192 + tid * 16;
      int row = off >> 9, ch = (off >> 4) & 31;
      lds_load16((const char*)kg + (size_t)(kvb + row) * 512 + ((ch ^ (row & 7)) * 16), Kd + off);
    }
#pragma unroll
    for (int p = 0; p < 4; ++p) {   // VT tile [256][64]: rows 128B = 8 chunks
      int off = p * 8192 + tid * 16;
      int row = off >> 7, ch = (off >> 4) & 7;
      lds_load16((const char*)vtg + (size_t)row * 16384 + (size_t)kvb * 2 + ((ch ^ (row & 7)) * 16),
                 Vd + off);
    }
  };

  stage(0, kb0);   // prologue

  for (int kt = 0; kt < nt; ++kt) {
    int cur = kt & 1;
    if (kt + 1 < nt) {
      stage(cur ^ 1, kb0 + (kt + 1) * 64);
      asm volatile("s_waitcnt vmcnt(8)" ::: "memory");   // older 8 (cur tile) complete
    } else {
      asm volatile("s_waitcnt vmcnt(0)" ::: "memory");
    }
    __builtin_amdgcn_s_barrier();                        // cur tile visible to all waves
    char* Kl = smem + cur * 65536;
    char* Vl = Kl + 32768;

    // S = Q*K^T (scale pre-folded into Wq)
    f32x4 s4[4];
#pragma unroll
    for (int it = 0; it < 4; ++it) s4[it] = (f32x4){0.f, 0.f, 0.f, 0.f};
#pragma unroll
    for (int ds = 0; ds < 8; ++ds)
#pragma unroll
      for (int it = 0; it < 4; ++it) {
        int krow = it * 16 + r15;
        bh8 kf = *(const bh8*)(Kl + krow * 512 + (((ds * 4 + g) ^ (krow & 7)) * 16));
        s4[it] = __builtin_amdgcn_mfma_f32_16x16x32_bf16(qf[ds], kf, s4[it], 0, 0, 0);
      }

    // online softmax over 64 keys (rows live in 16-lane groups)
    float rmax[4];
#pragma unroll
    for (int r = 0; r < 4; ++r)
      rmax[r] = fmaxf(fmaxf(s4[0][r], s4[1][r]), fmaxf(s4[2][r], s4[3][r]));
#pragma unroll
    for (int d = 1; d < 16; d <<= 1)
#pragma unroll
      for (int r = 0; r < 4; ++r) rmax[r] = fmaxf(rmax[r], __shfl_xor(rmax[r], d));
    float scl[4];
#pragma unroll
    for (int r = 0; r < 4; ++r) {
      float mn = fmaxf(m[r], rmax[r]);
      scl[r] = __expf(m[r] - mn);
      m[r] = mn;
    }
    float rsum[4] = {0.f, 0.f, 0.f, 0.f};
#pragma unroll
    for (int it = 0; it < 4; ++it)
#pragma unroll
      for (int r = 0; r < 4; ++r) {
        float pv = __expf(s4[it][r] - m[r]);
        s4[it][r] = pv;
        rsum[r] += pv;
      }
#pragma unroll
    for (int d = 1; d < 16; d <<= 1)
#pragma unroll
      for (int r = 0; r < 4; ++r) rsum[r] += __shfl_xor(rsum[r], d);
    f32x4 sv = {scl[0], scl[1], scl[2], scl[3]};
#pragma unroll
    for (int r = 0; r < 4; ++r) ls[r] = ls[r] * scl[r] + rsum[r];
#pragma unroll
    for (int dt = 0; dt < 16; ++dt) o[dt] *= sv;

    // P -> per-wave LDS (row stride 136B: banks 8g+2r+... fully spread, no XOR
    // needed; residual dword-paired 2-way is free). Wave-private: no barrier.
#pragma unroll
    for (int it = 0; it < 4; ++it)
#pragma unroll
      for (int r = 0; r < 4; ++r) {
        int prow = g * 4 + r;
        *(unsigned short*)(Pl + prow * 136 + (it * 16 + r15) * 2) = f2bf(s4[it][r]);
      }
    asm volatile("s_waitcnt lgkmcnt(0)" ::: "memory");
    bh8 pa[2];
#pragma unroll
    for (int ks = 0; ks < 2; ++ks) {
      const char* pb = Pl + r15 * 136 + ks * 64 + g * 16;   // 8B-aligned -> 2x b64
      bh4 lo = *(const bh4*)pb;
      bh4 hi = *(const bh4*)(pb + 8);
      bh8 t;
      t[0] = lo[0]; t[1] = lo[1]; t[2] = lo[2]; t[3] = lo[3];
      t[4] = hi[0]; t[5] = hi[1]; t[6] = hi[2]; t[7] = hi[3];
      pa[ks] = t;
    }
#pragma unroll
    for (int ks = 0; ks < 2; ++ks)
#pragma unroll
      for (int dt = 0; dt < 16; ++dt) {
        int vrow = dt * 16 + r15;
        bh8 vf = *(const bh8*)(Vl + vrow * 128 + (((ks * 4 + g) ^ (vrow & 7)) * 16));
        o[dt] = __builtin_amdgcn_mfma_f32_16x16x32_bf16(pa[ks], vf, o[dt], 0, 0, 0);
      }

    asm volatile("s_waitcnt lgkmcnt(0)" ::: "memory");   // all LDS reads landed
    __builtin_amdgcn_s_barrier();                        // safe to overwrite cur next iter
  }

  // partials
  int nrow = qrow0 + g * 4;
  float* ob = Op + ((size_t)s * 8192 + nrow) * 256 + r15;
#pragma unroll
  for (int r = 0; r < 4; ++r)
#pragma unroll
    for (int dt = 0; dt < 16; ++dt) ob[(size_t)r * 256 + dt * 16] = o[dt][r];
  if (r15 == 0) {
#pragma unroll
    for (int r = 0; r < 4; ++r) {
      mp[(size_t)s * 8192 + nrow + r] = m[r];
      lp[(size_t)s * 8192 + nrow + r] = ls[r];
    }
  }
}

// ---------------------------------------------------------------------------
// Split-K combine + normalize + output transpose to (t, d, p).
__global__ __launch_bounds__(256) void k_combine(
    const float* __restrict__ Op, const float* __restrict__ mp,
    const float* __restrict__ lp, float* __restrict__ out, int S) {
  __shared__ float wsc[4 * 256];
  __shared__ float lt[32 * 257];
  int t = blockIdx.x, dc = blockIdx.y, tid = threadIdx.x;
  {
    int n = t * 256 + tid;
    float mt = -INFINITY;
#pragma unroll 4
    for (int s = 0; s < 4; ++s)
      if (s < S) mt = fmaxf(mt, mp[(size_t)s * 8192 + n]);
    float den = 0.f;
#pragma unroll 4
    for (int s = 0; s < 4; ++s)
      if (s < S) den += __expf(mp[(size_t)s * 8192 + n] - mt) * lp[(size_t)s * 8192 + n];
    float inv = 1.0f / den;
#pragma unroll 4
    for (int s = 0; s < 4; ++s)
      if (s < S) wsc[s * 256 + tid] = __expf(mp[(size_t)s * 8192 + n] - mt) * inv;
  }
  __syncthreads();
  int dl = tid & 31, pg8 = tid >> 5;   // 32 d-lanes x 8 p-rows per pass
  for (int pg = 0; pg < 32; ++pg) {
    int p = pg * 8 + pg8;
    int n = t * 256 + p;
    float a = 0.f;
#pragma unroll 4
    for (int s = 0; s < 4; ++s)
      if (s < S) a += wsc[s * 256 + p] * Op[((size_t)s * 8192 + n) * 256 + dc * 32 + dl];
    lt[dl * 257 + p] = a;
  }
  __syncthreads();
  int d8 = tid >> 5, p0 = (tid & 31) * 8;
#pragma unroll
  for (int jj = 0; jj < 4; ++jj) {
    int dd = jj * 8 + d8;
    float4 v0, v1;
    v0.x = lt[dd * 257 + p0 + 0]; v0.y = lt[dd * 257 + p0 + 1];
    v0.z = lt[dd * 257 + p0 + 2]; v0.w = lt[dd * 257 + p0 + 3];
    v1.x = lt[dd * 257 + p0 + 4]; v1.y = lt[dd * 257 + p0 + 5];
    v1.z = lt[dd * 257 + p0 + 6]; v1.w = lt[dd * 257 + p0 + 7];
    float* ob = out + (size_t)t * 65536 + (size_t)(dc * 32 + dd) * 256 + p0;
    *(float4*)ob = v0;
    *(float4*)(ob + 4) = v1;
  }
}

// ---------------------------------------------------------------------------
extern "C" void kernel_launch(void* const* d_in, const int* in_sizes, int n_in,
                              void* d_out, int out_size, void* d_ws, size_t ws_size,
                              hipStream_t stream) {
  const float* hidden = (const float*)d_in[0];
  const float* Wq = (const float*)d_in[1];
  const float* Wk = (const float*)d_in[2];
  const float* Wv = (const float*)d_in[3];
  float* out = (float*)d_out;
  char* ws = (char*)d_ws;

  const size_t off_x  = 0;                               // x_bf16: 4MB
  const size_t off_wt = 4ull << 20;                      // 3 x 128KB
  const size_t off_q  = off_wt + 3ull * 131072;
  const size_t off_k  = off_q + 8192ull * 256 * 2;
  const size_t off_vt = off_k + 8192ull * 256 * 2;
  const size_t off_O  = off_vt + 8192ull * 256 * 2;

  int S = 4;
  {
    auto need = [&](int s) {
      return off_O + (size_t)s * 8192 * 256 * 4 + (size_t)s * 8192 * 4 * 2;
    };
    if (ws_size < need(4)) S = 2;
    if (ws_size < need(2)) S = 1;
  }
  size_t off_m = off_O + (size_t)S * 8192 * 256 * 4;
  size_t off_l = off_m + (size_t)S * 8192 * 4;

  unsigned short* xb  = (unsigned short*)(ws + off_x);
  unsigned short* wt  = (unsigned short*)(ws + off_wt);
  unsigned short* qb  = (unsigned short*)(ws + off_q);
  unsigned short* kb  = (unsigned short*)(ws + off_k);
  unsigned short* vtb = (unsigned short*)(ws + off_vt);
  float* Op = (float*)(ws + off_O);
  float* mp = (float*)(ws + off_m);
  float* lp = (float*)(ws + off_l);
  int shift = (S == 4) ? 2 : (S == 2 ? 1 : 0);
  int KS = 8192 / S;

  const int attn_lds = 131072 + 8 * 2176;   // K/V dbuf 128KB + P 17KB = 148480
  hipFuncSetAttribute((const void*)k_attn, hipFuncAttributeMaxDynamicSharedMemorySize,
                      attn_lds);

  k_transpose<<<dim3(35, 16), dim3(256), 0, stream>>>(hidden, Wq, Wk, Wv, xb, wt);
  k_gemm<<<dim3(64, 2, 3), dim3(256), 0, stream>>>(xb, wt, qb, kb, vtb);
  k_attn<<<dim3(64 * S), dim3(512), attn_lds, stream>>>(qb, kb, vtb, Op, mp, lp, S, shift, KS);
  k_combine<<<dim3(32, 8), dim3(256), 0, stream>>>(Op, mp, lp, out, S);
}